// Round 8
// baseline (125.346 us; speedup 1.0000x reference)
//
#include <hip/hip_runtime.h>

#define NQ     14
#define DIMQ   16384
#define NTROT  10
#define NWG    16
#define NTHR   256
#define NWAVE  64    // NWG * 4 waves

typedef float vfloat4 __attribute__((ext_vector_type(4)));

struct Smem {
    float2 slab[1024];   // 8 KiB staging slab (reused as float sumbuf)
    float2 tabLo[64];    // e^{i phi} for ZZ couplers 0..5
    float2 tabHi[128];   // e^{i phi} for ZZ couplers 6..12
    float  red[48];      // this WG's partial sums of the 42 constants
};

// ---------- device-coherent accessors (sc0 sc1 = agent scope, proven) ------
__device__ __forceinline__ float2 d2f2(double d) { union { double d; float2 f; } u; u.d = d; return u.f; }
__device__ __forceinline__ double f22d(float2 f) { union { double d; float2 f; } u; u.f = f; return u.d; }

__device__ __forceinline__ void ld4c(const float2* p, float2 r[4]) {
    vfloat4 a, b;
    asm volatile("global_load_dwordx4 %0, %2, off sc0 sc1\n\t"
                 "global_load_dwordx4 %1, %2, off offset:16 sc0 sc1\n\t"
                 "s_waitcnt vmcnt(0)"
                 : "=&v"(a), "=&v"(b) : "v"(p) : "memory");
    r[0] = make_float2(a.x, a.y); r[1] = make_float2(a.z, a.w);
    r[2] = make_float2(b.x, b.y); r[3] = make_float2(b.z, b.w);
}
__device__ __forceinline__ void st4c(float2* p, const float2 r[4]) {
    vfloat4 a, b;
    a.x = r[0].x; a.y = r[0].y; a.z = r[1].x; a.w = r[1].y;
    b.x = r[2].x; b.y = r[2].y; b.z = r[3].x; b.w = r[3].y;
    asm volatile("global_store_dwordx4 %0, %1, off sc0 sc1\n\t"
                 "global_store_dwordx4 %0, %2, off offset:16 sc0 sc1"
                 : : "v"(p), "v"(a), "v"(b) : "memory");
}
__device__ __forceinline__ void st2(float2* p, float2 v) {
    asm volatile("global_store_dwordx2 %0, %1, off sc0 sc1"
                 : : "v"(p), "v"(f22d(v)) : "memory");
}
__device__ __forceinline__ void stf(float* p, float v) {
    asm volatile("global_store_dword %0, %1, off sc0 sc1" : : "v"(p), "v"(v) : "memory");
}
__device__ __forceinline__ float ldf(const float* p) {
    float v;
    asm volatile("global_load_dword %0, %1, off sc0 sc1\n\ts_waitcnt vmcnt(0)"
                 : "=&v"(v) : "v"(p) : "memory");
    return v;
}
__device__ __forceinline__ void sti(int* p, int v) {
    asm volatile("global_store_dword %0, %1, off sc0 sc1" : : "v"(p), "v"(v) : "memory");
}
__device__ __forceinline__ int ldi(const int* p) {
    int v;
    asm volatile("global_load_dword %0, %1, off sc0 sc1\n\ts_waitcnt vmcnt(0)"
                 : "=&v"(v) : "v"(p) : "memory");
    return v;
}

// Wave-autonomous split barrier: 64 per-WAVE flags, phase-numbered (0xAA
// poison is negative => "not arrived", no init needed). arrive() drains THIS
// wave's psi stores (vmcnt is wave-scoped) then stores its flag; waitbar()
// has all 64 lanes load all 64 flags + ballot. Waiting on all wave-flags
// subsumes intra-WG synchronization for everything issued before arrive.
__device__ __forceinline__ void arrive(int* wf, int wid, int phase) {
    asm volatile("s_waitcnt vmcnt(0)" ::: "memory");
    if ((threadIdx.x & 63) == 0) sti(&wf[wid], phase);
}
__device__ __forceinline__ void waitbar(const int* wf, int phase) {
    const int lane = threadIdx.x & 63;
    for (;;) {
        int v = ldi(&wf[lane]);
        if (__ballot(v >= phase) == ~0ull) break;
    }
}

// ---------------- gate math ------------------------------------------------
__device__ __forceinline__ float2 cmulf(float2 a, float2 b) {
    return make_float2(a.x * b.x - a.y * b.y, a.x * b.y + a.y * b.x);
}
__device__ __forceinline__ void bfly(float2& p0, float2& p1, float c, float s) {
    float2 n0 = make_float2(c * p0.x + s * p1.y, c * p0.y - s * p1.x);
    float2 n1 = make_float2(c * p1.x + s * p0.y, c * p1.y - s * p0.x);
    p0 = n0; p1 = n1;
}
__device__ __forceinline__ void bfly_shfl(float2& p, int mask, float c, float s) {
    float qx = __shfl_xor(p.x, mask);
    float qy = __shfl_xor(p.y, mask);
    p = make_float2(c * p.x + s * qy, c * p.y - s * qx);
}
__device__ __forceinline__ void zz_apply(const Smem& sm, float2& a, int k) {
    int d = (k ^ (k >> 1)) & 0x1FFF;
    float2 rot = cmulf(sm.tabLo[d & 63], sm.tabHi[d >> 6]);
    a = cmulf(a, rot);
}
// mapping1: m=(t<<2)|j (regs = m bits 0,1)  <->  mapping2: m=t|(j<<8) (regs = m bits 8,9)
__device__ __forceinline__ void stage_12(float2* slab, float2 r[4], int t) {
    __syncthreads();
#pragma unroll
    for (int j = 0; j < 4; ++j) slab[(t << 2) | j] = r[j];
    __syncthreads();
#pragma unroll
    for (int j = 0; j < 4; ++j) r[j] = slab[t | (j << 8)];
}
__device__ __forceinline__ void stage_21(float2* slab, float2 r[4], int t) {
    __syncthreads();
#pragma unroll
    for (int j = 0; j < 4; ++j) slab[t | (j << 8)] = r[j];
    __syncthreads();
#pragma unroll
    for (int j = 0; j < 4; ++j) r[j] = slab[(t << 2) | j];
}
// Reduce triple i over the WG's slab; qubit at slab bit sb.
__device__ __forceinline__ void reduce_qubit(Smem& sm, int sb, int i, int t) {
    float cr = 0.f, ci = 0.f, z = 0.f;
#pragma unroll
    for (int j = 0; j < 4; ++j) {
        const int m = (t << 2) | j;
        const float2 a = sm.slab[m];
        const float n = a.x * a.x + a.y * a.y;
        if ((m >> sb) & 1) {
            z -= n;
        } else {
            z += n;
            const float2 b = sm.slab[m ^ (1 << sb)];
            cr += a.x * b.x + a.y * b.y;
            ci += a.x * b.y - a.y * b.x;
        }
    }
#pragma unroll
    for (int off = 32; off; off >>= 1) {
        cr += __shfl_down(cr, off);
        ci += __shfl_down(ci, off);
        z  += __shfl_down(z, off);
    }
    if ((t & 63) == 0) {
        atomicAdd(&sm.red[3 * i + 0], cr);
        atomicAdd(&sm.red[3 * i + 1], ci);
        atomicAdd(&sm.red[3 * i + 2], z);
    }
}

// ---- Layout A: k = (w<<10)|m. WG w = qubits 10..13; local = qubits 0..9.
// Leftover from B' = RX_s{4..7} (lane masks 4..32).
template <bool FIRST>
__device__ void phaseA(Smem& sm, float2* psi, int w, int t,
                       const float* c, const float* s) {
    float2 r[4];
    if (FIRST) {
#pragma unroll
        for (int j = 0; j < 4; ++j) r[j] = make_float2(0.0078125f, 0.0f);
    } else {
        ld4c(&psi[(w << 10) | (t << 2)], r);
#pragma unroll
        for (int b = 2; b < 6; ++b) {
#pragma unroll
            for (int j = 0; j < 4; ++j) bfly_shfl(r[j], 1 << b, c[2 + b], s[2 + b]);
        }
    }
    // ZZ_{s+1} + RX_{s+1}{0..9}
#pragma unroll
    for (int j = 0; j < 4; ++j) zz_apply(sm, r[j], (w << 10) | (t << 2) | j);
    bfly(r[0], r[1], c[0], s[0]); bfly(r[2], r[3], c[0], s[0]);
    bfly(r[0], r[2], c[1], s[1]); bfly(r[1], r[3], c[1], s[1]);
#pragma unroll
    for (int b = 0; b < 6; ++b) {
#pragma unroll
        for (int j = 0; j < 4; ++j) bfly_shfl(r[j], 1 << b, c[2 + b], s[2 + b]);
    }
    stage_12(sm.slab, r, t);   // mapping2: regs = q8,q9
    bfly(r[0], r[1], c[8], s[8]); bfly(r[2], r[3], c[8], s[8]);
    bfly(r[0], r[2], c[9], s[9]); bfly(r[1], r[3], c[9], s[9]);
#pragma unroll
    for (int j = 0; j < 4; ++j) st2(&psi[(w << 10) | t | (j << 8)], r[j]);
}

// ---- Layout B': k = (hi6<<8)|(w<<4)|lo4. WG w = qubits 4..7;
// local = {0..3, 8..13}; 32 B contiguous per thread, line-aligned chunks.
// RX_s{10..13}, ZZ_{s+1}, RX_{s+1}{0..3, 8..13}. Leftover: RX_{s+1}{4..7}.
// KEEPSLAB: leave final r in slab (mapping1) for the post-arrive reduction.
template <bool KEEPSLAB>
__device__ void phaseB(Smem& sm, float2* psi, int w, int t,
                       const float* c, const float* s) {
    float2 r[4];
    const int kbase = ((t >> 2) << 8) | (w << 4) | ((t & 3) << 2);
    ld4c(&psi[kbase], r);
#pragma unroll
    for (int j = 0; j < 4; ++j) bfly_shfl(r[j], 16, c[10], s[10]);
#pragma unroll
    for (int j = 0; j < 4; ++j) bfly_shfl(r[j], 32, c[11], s[11]);
    stage_12(sm.slab, r, t);   // mapping2: regs = q12,q13
    bfly(r[0], r[1], c[12], s[12]); bfly(r[2], r[3], c[12], s[12]);
    bfly(r[0], r[2], c[13], s[13]); bfly(r[1], r[3], c[13], s[13]);
#pragma unroll
    for (int j = 0; j < 4; ++j) {
        const int m = t | (j << 8);
        zz_apply(sm, r[j], ((m >> 4) << 8) | (w << 4) | (m & 15));
    }
    bfly(r[0], r[1], c[12], s[12]); bfly(r[2], r[3], c[12], s[12]);
    bfly(r[0], r[2], c[13], s[13]); bfly(r[1], r[3], c[13], s[13]);
#pragma unroll
    for (int b = 0; b < 4; ++b) {
#pragma unroll
        for (int j = 0; j < 4; ++j) bfly_shfl(r[j], 1 << b, c[b], s[b]);
    }
#pragma unroll
    for (int j = 0; j < 4; ++j) bfly_shfl(r[j], 16, c[8], s[8]);
#pragma unroll
    for (int j = 0; j < 4; ++j) bfly_shfl(r[j], 32, c[9], s[9]);
    stage_21(sm.slab, r, t);   // back to mapping1
#pragma unroll
    for (int j = 0; j < 4; ++j) bfly_shfl(r[j], 16, c[10], s[10]);
#pragma unroll
    for (int j = 0; j < 4; ++j) bfly_shfl(r[j], 32, c[11], s[11]);
    st4c(&psi[kbase], r);
    if (KEEPSLAB) {
        // slab[(t<<2)|j] last read by this same thread in stage_21 — safe
#pragma unroll
        for (int j = 0; j < 4; ++j) sm.slab[(t << 2) | j] = r[j];
    }
}

extern "C" __global__ void __launch_bounds__(NTHR)
qr_all(const float* __restrict__ x, const float* __restrict__ J,
       const float* __restrict__ g, float* __restrict__ out,
       float2* __restrict__ psi, float* __restrict__ P,
       int* __restrict__ wf) {
    __shared__ Smem sm;
    const int w = blockIdx.x;
    const int t = threadIdx.x;
    const int wid = (w << 2) | (t >> 6);
    const float dt = 0.1f;   // EVO_TIME / N_TROTTER

    if (t < 64) {
        float phi = 0.0f;
        for (int i = 0; i < 6; ++i) {
            const float h = 0.5f * J[i] * dt;
            phi += ((t >> i) & 1) ? h : -h;
        }
        float sn, cs; __sincosf(phi, &sn, &cs);
        sm.tabLo[t] = make_float2(cs, sn);
    } else if (t < 192) {
        const int v = t - 64;
        float phi = 0.0f;
        for (int i = 0; i < 7; ++i) {
            const float h = 0.5f * J[6 + i] * dt;
            phi += ((v >> i) & 1) ? h : -h;
        }
        float sn, cs; __sincosf(phi, &sn, &cs);
        sm.tabHi[v] = make_float2(cs, sn);
    }
    if (t < 48) sm.red[t] = 0.0f;
    float cc[NQ], ss[NQ];
#pragma unroll
    for (int i = 0; i < NQ; ++i) __sincosf(0.5f * g[i] * dt, &ss[i], &cc[i]);
    __syncthreads();

    int bar = 0;
    // Phase 1 (A): init + ZZ_1 + RX_1{0..9}
    phaseA<true>(sm, psi, w, t, cc, ss);
    arrive(wf, wid, ++bar);
    // Overlap phase-1 wait: precompute epilogue sincos (x is input-ready).
    // 2048*14 tasks / 4096 threads = exactly 7 per thread.
    float esn[7], ecs[7];
#pragma unroll
    for (int k = 0; k < 7; ++k) {
        const int task = w * NTHR + t + (k << 12);
        const int b = task / NQ;
        const int i = task - b * NQ;
        __sincosf(x[b * NQ + 13 - i], &esn[k], &ecs[k]);
    }
    waitbar(wf, bar);

    // Phases 2..10: B' on odd sstep, A on even
    for (int sstep = 1; sstep <= 9; ++sstep) {
        if (sstep & 1) {
            if (sstep == 9) {
                phaseB<true>(sm, psi, w, t, cc, ss);
                arrive(wf, wid, ++bar);
                // Overlap: reductions for q NOT in {4..7} (leftover RX{4..7}
                // commutes). Slab bits: q0..3 -> 0..3, q8..13 -> 4..9.
                __syncthreads();
#pragma unroll
                for (int q = 0; q <= 3; ++q) reduce_qubit(sm, q, 13 - q, t);
#pragma unroll
                for (int q = 8; q <= 13; ++q) reduce_qubit(sm, q - 4, 13 - q, t);
                waitbar(wf, bar);
            } else {
                phaseB<false>(sm, psi, w, t, cc, ss);
                arrive(wf, wid, ++bar);
                waitbar(wf, bar);
            }
        } else {
            phaseA<false>(sm, psi, w, t, cc, ss);
            arrive(wf, wid, ++bar);
            waitbar(wf, bar);
        }
    }

    // Phase 11 (A): leftover RX_10{4..7} + reductions q4..7 + partial store
    {
        float2 r[4];
        ld4c(&psi[(w << 10) | (t << 2)], r);
#pragma unroll
        for (int b = 2; b < 6; ++b) {
#pragma unroll
            for (int j = 0; j < 4; ++j) bfly_shfl(r[j], 1 << b, cc[2 + b], ss[2 + b]);
        }
        __syncthreads();
#pragma unroll
        for (int j = 0; j < 4; ++j) sm.slab[(t << 2) | j] = r[j];
        __syncthreads();
#pragma unroll
        for (int q = 4; q <= 7; ++q) reduce_qubit(sm, q, 13 - q, t);
        __syncthreads();
        if (t < 42) stf(&P[t * NWG + w], sm.red[t]);   // transposed partials
        arrive(wf, wid, ++bar);
        waitbar(wf, bar);
    }

    // Epilogue: coalesced gather of 672 partials -> LDS -> 42 sums
    float* sumbuf = (float*)sm.slab;
    for (int idx = t; idx < 42 * NWG; idx += NTHR) sumbuf[idx] = ldf(&P[idx]);
    __syncthreads();
    float cv = 0.0f;
    if (t < 42) {
#pragma unroll
        for (int k = 0; k < NWG; ++k) cv += sumbuf[t * NWG + k];
    }
    __syncthreads();
    if (t < 42) sm.red[t] = cv;
    __syncthreads();

    // Batched outputs (sincos precomputed during phase-1 wait)
#pragma unroll
    for (int k = 0; k < 7; ++k) {
        const int task = w * NTHR + t + (k << 12);
        const int b = task / NQ;
        const int i = task - b * NQ;
        const float cr = sm.red[3 * i + 0];
        const float ci = sm.red[3 * i + 1];
        const float zz = sm.red[3 * i + 2];
        const float sn = esn[k], cs = ecs[k];
        float* o = out + b * (3 * NQ) + 3 * i;
        o[0] = 2.0f * (cs * cr - sn * ci);
        o[1] = 2.0f * (sn * cr + cs * ci);
        o[2] = zz;
    }
}

extern "C" void kernel_launch(void* const* d_in, const int* in_sizes, int n_in,
                              void* d_out, int out_size, void* d_ws, size_t ws_size,
                              hipStream_t stream) {
    const float* x = (const float*)d_in[0];
    const float* J = (const float*)d_in[1];
    const float* g = (const float*)d_in[2];
    float* out = (float*)d_out;
    char* ws   = (char*)d_ws;
    float2* psi = (float2*)ws;                                  // 128 KiB
    int*    wf  = (int*)(ws + DIMQ * sizeof(float2));           // 64 wave flags
    float*  P   = (float*)(ws + DIMQ * sizeof(float2) + 256);   // 672 floats
    (void)in_sizes; (void)n_in; (void)out_size; (void)ws_size;

    // Single dispatch; no memset needed (phase-numbered flags, poison-safe).
    hipLaunchKernelGGL(qr_all, dim3(NWG), dim3(NTHR), 0, stream,
                       x, J, g, out, psi, P, wf);
}

// Round 9
// 111.510 us; speedup vs baseline: 1.1241x; 1.1241x over previous
//
#include <hip/hip_runtime.h>

#define NQ     14
#define DIMQ   16384
#define NTROT  10
#define NWG    16
#define NTHR   256
#define NWAVE  64    // NWG * 4 waves

typedef float vfloat4 __attribute__((ext_vector_type(4)));

struct Smem {
    float2 slab[1024];   // 8 KiB staging slab (reused as float sumbuf)
    float2 tabLo[64];    // e^{i phi} for ZZ couplers 0..5
    float2 tabHi[128];   // e^{i phi} for ZZ couplers 6..12
    float  red[48];      // this WG's partial sums of the 42 constants
};

// ---------- device-coherent accessors (sc0 sc1 = agent scope, proven) ------
__device__ __forceinline__ float2 d2f2(double d) { union { double d; float2 f; } u; u.d = d; return u.f; }
__device__ __forceinline__ double f22d(float2 f) { union { double d; float2 f; } u; u.f = f; return u.d; }

__device__ __forceinline__ void ld4c(const float2* p, float2 r[4]) {
    vfloat4 a, b;
    asm volatile("global_load_dwordx4 %0, %2, off sc0 sc1\n\t"
                 "global_load_dwordx4 %1, %2, off offset:16 sc0 sc1\n\t"
                 "s_waitcnt vmcnt(0)"
                 : "=&v"(a), "=&v"(b) : "v"(p) : "memory");
    r[0] = make_float2(a.x, a.y); r[1] = make_float2(a.z, a.w);
    r[2] = make_float2(b.x, b.y); r[3] = make_float2(b.z, b.w);
}
__device__ __forceinline__ void st4c(float2* p, const float2 r[4]) {
    vfloat4 a, b;
    a.x = r[0].x; a.y = r[0].y; a.z = r[1].x; a.w = r[1].y;
    b.x = r[2].x; b.y = r[2].y; b.z = r[3].x; b.w = r[3].y;
    asm volatile("global_store_dwordx4 %0, %1, off sc0 sc1\n\t"
                 "global_store_dwordx4 %0, %2, off offset:16 sc0 sc1"
                 : : "v"(p), "v"(a), "v"(b) : "memory");
}
__device__ __forceinline__ void st2(float2* p, float2 v) {
    asm volatile("global_store_dwordx2 %0, %1, off sc0 sc1"
                 : : "v"(p), "v"(f22d(v)) : "memory");
}
__device__ __forceinline__ void stf(float* p, float v) {
    asm volatile("global_store_dword %0, %1, off sc0 sc1" : : "v"(p), "v"(v) : "memory");
}
__device__ __forceinline__ void sti(int* p, int v) {
    asm volatile("global_store_dword %0, %1, off sc0 sc1" : : "v"(p), "v"(v) : "memory");
}
// 3 batched loads (stride 256 floats), one waitcnt — epilogue partials gather
__device__ __forceinline__ void ldf3(const float* p, float& r0, float& r1, float& r2) {
    asm volatile("global_load_dword %0, %3, off sc0 sc1\n\t"
                 "global_load_dword %1, %3, off offset:1024 sc0 sc1\n\t"
                 "global_load_dword %2, %3, off offset:2048 sc0 sc1\n\t"
                 "s_waitcnt vmcnt(0)"
                 : "=&v"(r0), "=&v"(r1), "=&v"(r2) : "v"(p) : "memory");
}

// --- barrier -----------------------------------------------------------
// arrive: each WAVE drains its own psi stores (vmcnt is wave-scoped) and
// stores its per-wave flag — no __syncthreads needed before arrival.
// Phase-numbered flags: 0xAA poison is negative => "not arrived", no init.
__device__ __forceinline__ void arrive(int* wf, int wid, int phase) {
    asm volatile("s_waitcnt vmcnt(0)" ::: "memory");
    if ((threadIdx.x & 63) == 0) sti(&wf[wid], phase);
}
// Pipelined 2-deep poll: ONLY wave 0 of each WG; its 64 lanes read the 64
// per-wave flags. Two flag loads stay in flight; check the oldest each
// iteration -> detection granularity ~ half a MALL round trip.
__device__ __forceinline__ void waitpoll(const int* wf, int phase) {
    const int* p = &wf[threadIdx.x & 63];
    int v0, v1;
    asm volatile(
        "global_load_dword %0, %2, off sc0 sc1\n\t"
        "global_load_dword %1, %2, off sc0 sc1\n\t"
        "1:\n\t"
        "s_waitcnt vmcnt(1)\n\t"
        "v_cmp_gt_i32 vcc, %3, %0\n\t"     // pending = phase > flag
        "s_cbranch_vccz 2f\n\t"
        "global_load_dword %0, %2, off sc0 sc1\n\t"
        "s_waitcnt vmcnt(1)\n\t"
        "v_cmp_gt_i32 vcc, %3, %1\n\t"
        "s_cbranch_vccz 2f\n\t"
        "global_load_dword %1, %2, off sc0 sc1\n\t"
        "s_branch 1b\n\t"
        "2:\n\t"
        "s_waitcnt vmcnt(0)"
        : "=&v"(v0), "=&v"(v1)
        : "v"(p), "s"(phase)
        : "memory", "vcc");
}
__device__ __forceinline__ void waitrel(const int* wf, int phase) {
    if (threadIdx.x < 64) waitpoll(wf, phase);
    __syncthreads();
}

// ---------------- gate math ------------------------------------------------
__device__ __forceinline__ float2 cmulf(float2 a, float2 b) {
    return make_float2(a.x * b.x - a.y * b.y, a.x * b.y + a.y * b.x);
}
__device__ __forceinline__ void bfly(float2& p0, float2& p1, float c, float s) {
    float2 n0 = make_float2(c * p0.x + s * p1.y, c * p0.y - s * p1.x);
    float2 n1 = make_float2(c * p1.x + s * p0.y, c * p1.y - s * p0.x);
    p0 = n0; p1 = n1;
}
__device__ __forceinline__ void bfly_shfl(float2& p, int mask, float c, float s) {
    float qx = __shfl_xor(p.x, mask);
    float qy = __shfl_xor(p.y, mask);
    p = make_float2(c * p.x + s * qy, c * p.y - s * qx);
}
__device__ __forceinline__ void zz_apply(const Smem& sm, float2& a, int k) {
    int d = (k ^ (k >> 1)) & 0x1FFF;
    float2 rot = cmulf(sm.tabLo[d & 63], sm.tabHi[d >> 6]);
    a = cmulf(a, rot);
}
// mapping1: m=(t<<2)|j (regs = m bits 0,1)  <->  mapping2: m=t|(j<<8)
__device__ __forceinline__ void stage_12(float2* slab, float2 r[4], int t) {
    __syncthreads();
#pragma unroll
    for (int j = 0; j < 4; ++j) slab[(t << 2) | j] = r[j];
    __syncthreads();
#pragma unroll
    for (int j = 0; j < 4; ++j) r[j] = slab[t | (j << 8)];
}
__device__ __forceinline__ void stage_21(float2* slab, float2 r[4], int t) {
    __syncthreads();
#pragma unroll
    for (int j = 0; j < 4; ++j) slab[t | (j << 8)] = r[j];
    __syncthreads();
#pragma unroll
    for (int j = 0; j < 4; ++j) r[j] = slab[(t << 2) | j];
}
// Reduce triple i over the WG's slab; qubit at slab bit sb.
__device__ __forceinline__ void reduce_qubit(Smem& sm, int sb, int i, int t) {
    float cr = 0.f, ci = 0.f, z = 0.f;
#pragma unroll
    for (int j = 0; j < 4; ++j) {
        const int m = (t << 2) | j;
        const float2 a = sm.slab[m];
        const float n = a.x * a.x + a.y * a.y;
        if ((m >> sb) & 1) {
            z -= n;
        } else {
            z += n;
            const float2 b = sm.slab[m ^ (1 << sb)];
            cr += a.x * b.x + a.y * b.y;
            ci += a.x * b.y - a.y * b.x;
        }
    }
#pragma unroll
    for (int off = 32; off; off >>= 1) {
        cr += __shfl_down(cr, off);
        ci += __shfl_down(ci, off);
        z  += __shfl_down(z, off);
    }
    if ((t & 63) == 0) {
        atomicAdd(&sm.red[3 * i + 0], cr);
        atomicAdd(&sm.red[3 * i + 1], ci);
        atomicAdd(&sm.red[3 * i + 2], z);
    }
}

// ---- Layout A: k = (w<<10)|m. WG w = qubits 10..13; local 0..9.
template <bool FIRST>
__device__ void phaseA(Smem& sm, float2* psi, int w, int t,
                       const float* c, const float* s) {
    float2 r[4];
    if (FIRST) {
#pragma unroll
        for (int j = 0; j < 4; ++j) r[j] = make_float2(0.0078125f, 0.0f);
    } else {
        ld4c(&psi[(w << 10) | (t << 2)], r);
#pragma unroll
        for (int b = 2; b < 6; ++b) {   // leftover RX_s{4..7}
#pragma unroll
            for (int j = 0; j < 4; ++j) bfly_shfl(r[j], 1 << b, c[2 + b], s[2 + b]);
        }
    }
#pragma unroll
    for (int j = 0; j < 4; ++j) zz_apply(sm, r[j], (w << 10) | (t << 2) | j);
    bfly(r[0], r[1], c[0], s[0]); bfly(r[2], r[3], c[0], s[0]);
    bfly(r[0], r[2], c[1], s[1]); bfly(r[1], r[3], c[1], s[1]);
#pragma unroll
    for (int b = 0; b < 6; ++b) {
#pragma unroll
        for (int j = 0; j < 4; ++j) bfly_shfl(r[j], 1 << b, c[2 + b], s[2 + b]);
    }
    stage_12(sm.slab, r, t);   // mapping2: regs = q8,q9
    bfly(r[0], r[1], c[8], s[8]); bfly(r[2], r[3], c[8], s[8]);
    bfly(r[0], r[2], c[9], s[9]); bfly(r[1], r[3], c[9], s[9]);
#pragma unroll
    for (int j = 0; j < 4; ++j) st2(&psi[(w << 10) | t | (j << 8)], r[j]);
}

// ---- Layout B': k = (hi6<<8)|(w<<4)|lo4. WG w = qubits 4..7;
// local {0..3,8..13}; 32 B contiguous per thread.
// RX_s{10..13}, ZZ_{s+1}, RX_{s+1}{0..3,8..13}. Leftover: RX_{s+1}{4..7}.
template <bool KEEPSLAB>
__device__ void phaseB(Smem& sm, float2* psi, int w, int t,
                       const float* c, const float* s) {
    float2 r[4];
    const int kbase = ((t >> 2) << 8) | (w << 4) | ((t & 3) << 2);
    ld4c(&psi[kbase], r);
#pragma unroll
    for (int j = 0; j < 4; ++j) bfly_shfl(r[j], 16, c[10], s[10]);
#pragma unroll
    for (int j = 0; j < 4; ++j) bfly_shfl(r[j], 32, c[11], s[11]);
    stage_12(sm.slab, r, t);   // mapping2: regs = q12,q13
    bfly(r[0], r[1], c[12], s[12]); bfly(r[2], r[3], c[12], s[12]);
    bfly(r[0], r[2], c[13], s[13]); bfly(r[1], r[3], c[13], s[13]);
#pragma unroll
    for (int j = 0; j < 4; ++j) {
        const int m = t | (j << 8);
        zz_apply(sm, r[j], ((m >> 4) << 8) | (w << 4) | (m & 15));
    }
    bfly(r[0], r[1], c[12], s[12]); bfly(r[2], r[3], c[12], s[12]);
    bfly(r[0], r[2], c[13], s[13]); bfly(r[1], r[3], c[13], s[13]);
#pragma unroll
    for (int b = 0; b < 4; ++b) {
#pragma unroll
        for (int j = 0; j < 4; ++j) bfly_shfl(r[j], 1 << b, c[b], s[b]);
    }
#pragma unroll
    for (int j = 0; j < 4; ++j) bfly_shfl(r[j], 16, c[8], s[8]);
#pragma unroll
    for (int j = 0; j < 4; ++j) bfly_shfl(r[j], 32, c[9], s[9]);
    stage_21(sm.slab, r, t);   // back to mapping1
#pragma unroll
    for (int j = 0; j < 4; ++j) bfly_shfl(r[j], 16, c[10], s[10]);
#pragma unroll
    for (int j = 0; j < 4; ++j) bfly_shfl(r[j], 32, c[11], s[11]);
    st4c(&psi[kbase], r);
    if (KEEPSLAB) {
        // slab[(t<<2)|j] last read by this same thread in stage_21 — safe
#pragma unroll
        for (int j = 0; j < 4; ++j) sm.slab[(t << 2) | j] = r[j];
    }
}

extern "C" __global__ void __launch_bounds__(NTHR)
qr_all(const float* __restrict__ x, const float* __restrict__ J,
       const float* __restrict__ g, float* __restrict__ out,
       float2* __restrict__ psi, float* __restrict__ P,
       int* __restrict__ wf) {
    __shared__ Smem sm;
    const int w = blockIdx.x;
    const int t = threadIdx.x;
    const int wid = (w << 2) | (t >> 6);
    const float dt = 0.1f;   // EVO_TIME / N_TROTTER

    if (t < 64) {
        float phi = 0.0f;
        for (int i = 0; i < 6; ++i) {
            const float h = 0.5f * J[i] * dt;
            phi += ((t >> i) & 1) ? h : -h;
        }
        float sn, cs; __sincosf(phi, &sn, &cs);
        sm.tabLo[t] = make_float2(cs, sn);
    } else if (t < 192) {
        const int v = t - 64;
        float phi = 0.0f;
        for (int i = 0; i < 7; ++i) {
            const float h = 0.5f * J[6 + i] * dt;
            phi += ((v >> i) & 1) ? h : -h;
        }
        float sn, cs; __sincosf(phi, &sn, &cs);
        sm.tabHi[v] = make_float2(cs, sn);
    }
    if (t < 48) sm.red[t] = 0.0f;
    float cc[NQ], ss[NQ];
#pragma unroll
    for (int i = 0; i < NQ; ++i) __sincosf(0.5f * g[i] * dt, &ss[i], &cc[i]);
    __syncthreads();

    int bar = 0;
    // Phase 1 (A): init + ZZ_1 + RX_1{0..9}
    phaseA<true>(sm, psi, w, t, cc, ss);
    arrive(wf, wid, ++bar);
    // Overlap phase-1 wait: precompute epilogue sincos (7 tasks/thread).
    float esn[7], ecs[7];
#pragma unroll
    for (int k = 0; k < 7; ++k) {
        const int task = w * NTHR + t + (k << 12);
        const int b = task / NQ;
        const int i = task - b * NQ;
        __sincosf(x[b * NQ + 13 - i], &esn[k], &ecs[k]);
    }
    waitrel(wf, bar);

    // Phases 2..10: B' on odd sstep, A on even
    for (int sstep = 1; sstep <= 9; ++sstep) {
        if (sstep & 1) {
            if (sstep == 9) {
                phaseB<true>(sm, psi, w, t, cc, ss);
                arrive(wf, wid, ++bar);
                // Overlap: reductions for q NOT in {4..7} (leftover commutes).
                // Slab bits: q0..3 -> 0..3, q8..13 -> 4..9.
                __syncthreads();
#pragma unroll
                for (int q = 0; q <= 3; ++q) reduce_qubit(sm, q, 13 - q, t);
#pragma unroll
                for (int q = 8; q <= 13; ++q) reduce_qubit(sm, q - 4, 13 - q, t);
                waitrel(wf, bar);
            } else {
                phaseB<false>(sm, psi, w, t, cc, ss);
                arrive(wf, wid, ++bar);
                waitrel(wf, bar);
            }
        } else {
            phaseA<false>(sm, psi, w, t, cc, ss);
            arrive(wf, wid, ++bar);
            waitrel(wf, bar);
        }
    }

    // Phase 11 (A): leftover RX_10{4..7} + reductions q4..7 + partial store
    {
        float2 r[4];
        ld4c(&psi[(w << 10) | (t << 2)], r);
#pragma unroll
        for (int b = 2; b < 6; ++b) {
#pragma unroll
            for (int j = 0; j < 4; ++j) bfly_shfl(r[j], 1 << b, cc[2 + b], ss[2 + b]);
        }
        __syncthreads();
#pragma unroll
        for (int j = 0; j < 4; ++j) sm.slab[(t << 2) | j] = r[j];
        __syncthreads();
#pragma unroll
        for (int q = 4; q <= 7; ++q) reduce_qubit(sm, q, 13 - q, t);
        __syncthreads();
        if (t < 42) stf(&P[t * NWG + w], sm.red[t]);   // transposed partials
        arrive(wf, wid, ++bar);
        waitrel(wf, bar);
    }

    // Epilogue: batched gather of 768 partial slots (rows 42..47 unused) ->
    // LDS -> 42 sums (unused rows summed but never read).
    float* sumbuf = (float*)sm.slab;
    {
        float r0, r1, r2;
        ldf3(&P[t], r0, r1, r2);
        sumbuf[t] = r0; sumbuf[t + 256] = r1; sumbuf[t + 512] = r2;
    }
    __syncthreads();
    float cv = 0.0f;
    if (t < 42) {
#pragma unroll
        for (int k = 0; k < NWG; ++k) cv += sumbuf[t * NWG + k];
    }
    __syncthreads();
    if (t < 42) sm.red[t] = cv;
    __syncthreads();

    // Batched outputs (sincos precomputed during phase-1 wait)
#pragma unroll
    for (int k = 0; k < 7; ++k) {
        const int task = w * NTHR + t + (k << 12);
        const int b = task / NQ;
        const int i = task - b * NQ;
        const float cr = sm.red[3 * i + 0];
        const float ci = sm.red[3 * i + 1];
        const float zz = sm.red[3 * i + 2];
        const float sn = esn[k], cs = ecs[k];
        float* o = out + b * (3 * NQ) + 3 * i;
        o[0] = 2.0f * (cs * cr - sn * ci);
        o[1] = 2.0f * (sn * cr + cs * ci);
        o[2] = zz;
    }
}

extern "C" void kernel_launch(void* const* d_in, const int* in_sizes, int n_in,
                              void* d_out, int out_size, void* d_ws, size_t ws_size,
                              hipStream_t stream) {
    const float* x = (const float*)d_in[0];
    const float* J = (const float*)d_in[1];
    const float* g = (const float*)d_in[2];
    float* out = (float*)d_out;
    char* ws   = (char*)d_ws;
    float2* psi = (float2*)ws;                                  // 128 KiB
    int*    wf  = (int*)(ws + DIMQ * sizeof(float2));           // 64 wave flags
    float*  P   = (float*)(ws + DIMQ * sizeof(float2) + 256);   // 768 floats
    (void)in_sizes; (void)n_in; (void)out_size; (void)ws_size;

    // Single dispatch; no memset needed (phase-numbered flags, poison-safe).
    hipLaunchKernelGGL(qr_all, dim3(NWG), dim3(NTHR), 0, stream,
                       x, J, g, out, psi, P, wf);
}

// Round 10
// 103.576 us; speedup vs baseline: 1.2102x; 1.0766x over previous
//
#include <hip/hip_runtime.h>

#define NQ     14
#define DIMQ   16384
#define NTROT  10
#define NWG    16
#define NTHR   256
#define NWAVE  64      // NWG * 4 waves
#define FSTR   64      // flag spacing in ints (256 B = own cache line)

typedef float vfloat4 __attribute__((ext_vector_type(4)));

struct Smem {
    float2 slab[1024];   // 8 KiB staging slab (reused as float sumbuf)
    float2 tabLo[64];    // e^{i phi} for ZZ couplers 0..5
    float2 tabHi[128];   // e^{i phi} for ZZ couplers 6..12
    float  red[48];      // this WG's partial sums of the 42 constants
};

// ---------- device-coherent accessors (sc0 sc1 = agent scope, proven) ------
__device__ __forceinline__ float2 d2f2(double d) { union { double d; float2 f; } u; u.d = d; return u.f; }
__device__ __forceinline__ double f22d(float2 f) { union { double d; float2 f; } u; u.f = f; return u.d; }

__device__ __forceinline__ void ld4c(const float2* p, float2 r[4]) {
    vfloat4 a, b;
    asm volatile("global_load_dwordx4 %0, %2, off sc0 sc1\n\t"
                 "global_load_dwordx4 %1, %2, off offset:16 sc0 sc1\n\t"
                 "s_waitcnt vmcnt(0)"
                 : "=&v"(a), "=&v"(b) : "v"(p) : "memory");
    r[0] = make_float2(a.x, a.y); r[1] = make_float2(a.z, a.w);
    r[2] = make_float2(b.x, b.y); r[3] = make_float2(b.z, b.w);
}
__device__ __forceinline__ void st4c(float2* p, const float2 r[4]) {
    vfloat4 a, b;
    a.x = r[0].x; a.y = r[0].y; a.z = r[1].x; a.w = r[1].y;
    b.x = r[2].x; b.y = r[2].y; b.z = r[3].x; b.w = r[3].y;
    asm volatile("global_store_dwordx4 %0, %1, off sc0 sc1\n\t"
                 "global_store_dwordx4 %0, %2, off offset:16 sc0 sc1"
                 : : "v"(p), "v"(a), "v"(b) : "memory");
}
__device__ __forceinline__ void st2(float2* p, float2 v) {
    asm volatile("global_store_dwordx2 %0, %1, off sc0 sc1"
                 : : "v"(p), "v"(f22d(v)) : "memory");
}
__device__ __forceinline__ void stf(float* p, float v) {
    asm volatile("global_store_dword %0, %1, off sc0 sc1" : : "v"(p), "v"(v) : "memory");
}
__device__ __forceinline__ void sti(int* p, int v) {
    asm volatile("global_store_dword %0, %1, off sc0 sc1" : : "v"(p), "v"(v) : "memory");
}
__device__ __forceinline__ int ldi(const int* p) {
    int v;
    asm volatile("global_load_dword %0, %1, off sc0 sc1\n\ts_waitcnt vmcnt(0)"
                 : "=&v"(v) : "v"(p) : "memory");
    return v;
}
// 3 batched loads (stride 1 KiB), one waitcnt — epilogue partials gather
__device__ __forceinline__ void ldf3(const float* p, float& r0, float& r1, float& r2) {
    asm volatile("global_load_dword %0, %3, off sc0 sc1\n\t"
                 "global_load_dword %1, %3, off offset:1024 sc0 sc1\n\t"
                 "global_load_dword %2, %3, off offset:2048 sc0 sc1\n\t"
                 "s_waitcnt vmcnt(0)"
                 : "=&v"(r0), "=&v"(r1), "=&v"(r2) : "v"(p) : "memory");
}

// --- barrier (R7-proven config + line-spread flags) ------------------------
// arrive: each WAVE drains its own psi stores (vmcnt is wave-scoped) and
// stores its per-wave flag into its OWN 256 B line. Phase-numbered flags:
// 0xAA poison is negative => "not arrived", no init needed.
__device__ __forceinline__ void arrive(int* wf, int wid, int phase) {
    asm volatile("s_waitcnt vmcnt(0)" ::: "memory");
    if ((threadIdx.x & 63) == 0) sti(&wf[wid * FSTR], phase);
}
// wait: ONLY wave 0 polls — 64 lanes load 64 flags (64 distinct lines),
// ballot, s_sleep(1) throttle (load-bearing: unthrottled polling queues
// ahead of arrival stores at the MALL — R8/R9 regressions).
__device__ __forceinline__ void waitrel(const int* wf, int phase) {
    if (threadIdx.x < 64) {
        const int* p = &wf[threadIdx.x * FSTR];
        for (;;) {
            int v = ldi(p);
            if (__ballot(v >= phase) == ~0ull) break;
            __builtin_amdgcn_s_sleep(1);
        }
    }
    __syncthreads();
}

// ---------------- gate math ------------------------------------------------
__device__ __forceinline__ float2 cmulf(float2 a, float2 b) {
    return make_float2(a.x * b.x - a.y * b.y, a.x * b.y + a.y * b.x);
}
__device__ __forceinline__ void bfly(float2& p0, float2& p1, float c, float s) {
    float2 n0 = make_float2(c * p0.x + s * p1.y, c * p0.y - s * p1.x);
    float2 n1 = make_float2(c * p1.x + s * p0.y, c * p1.y - s * p0.x);
    p0 = n0; p1 = n1;
}
__device__ __forceinline__ void bfly_shfl(float2& p, int mask, float c, float s) {
    float qx = __shfl_xor(p.x, mask);
    float qy = __shfl_xor(p.y, mask);
    p = make_float2(c * p.x + s * qy, c * p.y - s * qx);
}
__device__ __forceinline__ void zz_apply(const Smem& sm, float2& a, int k) {
    int d = (k ^ (k >> 1)) & 0x1FFF;
    float2 rot = cmulf(sm.tabLo[d & 63], sm.tabHi[d >> 6]);
    a = cmulf(a, rot);
}
// mapping1: m=(t<<2)|j (regs = m bits 0,1)  <->  mapping2: m=t|(j<<8)
__device__ __forceinline__ void stage_12(float2* slab, float2 r[4], int t) {
    __syncthreads();
#pragma unroll
    for (int j = 0; j < 4; ++j) slab[(t << 2) | j] = r[j];
    __syncthreads();
#pragma unroll
    for (int j = 0; j < 4; ++j) r[j] = slab[t | (j << 8)];
}
__device__ __forceinline__ void stage_21(float2* slab, float2 r[4], int t) {
    __syncthreads();
#pragma unroll
    for (int j = 0; j < 4; ++j) slab[t | (j << 8)] = r[j];
    __syncthreads();
#pragma unroll
    for (int j = 0; j < 4; ++j) r[j] = slab[(t << 2) | j];
}
// Reduce triple i over the WG's slab; qubit at slab bit sb.
__device__ __forceinline__ void reduce_qubit(Smem& sm, int sb, int i, int t) {
    float cr = 0.f, ci = 0.f, z = 0.f;
#pragma unroll
    for (int j = 0; j < 4; ++j) {
        const int m = (t << 2) | j;
        const float2 a = sm.slab[m];
        const float n = a.x * a.x + a.y * a.y;
        if ((m >> sb) & 1) {
            z -= n;
        } else {
            z += n;
            const float2 b = sm.slab[m ^ (1 << sb)];
            cr += a.x * b.x + a.y * b.y;
            ci += a.x * b.y - a.y * b.x;
        }
    }
#pragma unroll
    for (int off = 32; off; off >>= 1) {
        cr += __shfl_down(cr, off);
        ci += __shfl_down(ci, off);
        z  += __shfl_down(z, off);
    }
    if ((t & 63) == 0) {
        atomicAdd(&sm.red[3 * i + 0], cr);
        atomicAdd(&sm.red[3 * i + 1], ci);
        atomicAdd(&sm.red[3 * i + 2], z);
    }
}

// ---- Layout A: k = (w<<10)|m. WG w = qubits 10..13; local 0..9.
template <bool FIRST>
__device__ void phaseA(Smem& sm, float2* psi, int w, int t,
                       const float* c, const float* s) {
    float2 r[4];
    if (FIRST) {
#pragma unroll
        for (int j = 0; j < 4; ++j) r[j] = make_float2(0.0078125f, 0.0f);
    } else {
        ld4c(&psi[(w << 10) | (t << 2)], r);
#pragma unroll
        for (int b = 2; b < 6; ++b) {   // leftover RX_s{4..7}
#pragma unroll
            for (int j = 0; j < 4; ++j) bfly_shfl(r[j], 1 << b, c[2 + b], s[2 + b]);
        }
    }
#pragma unroll
    for (int j = 0; j < 4; ++j) zz_apply(sm, r[j], (w << 10) | (t << 2) | j);
    bfly(r[0], r[1], c[0], s[0]); bfly(r[2], r[3], c[0], s[0]);
    bfly(r[0], r[2], c[1], s[1]); bfly(r[1], r[3], c[1], s[1]);
#pragma unroll
    for (int b = 0; b < 6; ++b) {
#pragma unroll
        for (int j = 0; j < 4; ++j) bfly_shfl(r[j], 1 << b, c[2 + b], s[2 + b]);
    }
    stage_12(sm.slab, r, t);   // mapping2: regs = q8,q9
    bfly(r[0], r[1], c[8], s[8]); bfly(r[2], r[3], c[8], s[8]);
    bfly(r[0], r[2], c[9], s[9]); bfly(r[1], r[3], c[9], s[9]);
#pragma unroll
    for (int j = 0; j < 4; ++j) st2(&psi[(w << 10) | t | (j << 8)], r[j]);
}

// ---- Layout B': k = (hi6<<8)|(w<<4)|lo4. WG w = qubits 4..7;
// local {0..3,8..13}; 32 B contiguous per thread.
// RX_s{10..13}, ZZ_{s+1}, RX_{s+1}{0..3,8..13}. Leftover: RX_{s+1}{4..7}.
template <bool KEEPSLAB>
__device__ void phaseB(Smem& sm, float2* psi, int w, int t,
                       const float* c, const float* s) {
    float2 r[4];
    const int kbase = ((t >> 2) << 8) | (w << 4) | ((t & 3) << 2);
    ld4c(&psi[kbase], r);
#pragma unroll
    for (int j = 0; j < 4; ++j) bfly_shfl(r[j], 16, c[10], s[10]);
#pragma unroll
    for (int j = 0; j < 4; ++j) bfly_shfl(r[j], 32, c[11], s[11]);
    stage_12(sm.slab, r, t);   // mapping2: regs = q12,q13
    bfly(r[0], r[1], c[12], s[12]); bfly(r[2], r[3], c[12], s[12]);
    bfly(r[0], r[2], c[13], s[13]); bfly(r[1], r[3], c[13], s[13]);
#pragma unroll
    for (int j = 0; j < 4; ++j) {
        const int m = t | (j << 8);
        zz_apply(sm, r[j], ((m >> 4) << 8) | (w << 4) | (m & 15));
    }
    bfly(r[0], r[1], c[12], s[12]); bfly(r[2], r[3], c[12], s[12]);
    bfly(r[0], r[2], c[13], s[13]); bfly(r[1], r[3], c[13], s[13]);
#pragma unroll
    for (int b = 0; b < 4; ++b) {
#pragma unroll
        for (int j = 0; j < 4; ++j) bfly_shfl(r[j], 1 << b, c[b], s[b]);
    }
#pragma unroll
    for (int j = 0; j < 4; ++j) bfly_shfl(r[j], 16, c[8], s[8]);
#pragma unroll
    for (int j = 0; j < 4; ++j) bfly_shfl(r[j], 32, c[9], s[9]);
    stage_21(sm.slab, r, t);   // back to mapping1
#pragma unroll
    for (int j = 0; j < 4; ++j) bfly_shfl(r[j], 16, c[10], s[10]);
#pragma unroll
    for (int j = 0; j < 4; ++j) bfly_shfl(r[j], 32, c[11], s[11]);
    st4c(&psi[kbase], r);
    if (KEEPSLAB) {
        // slab[(t<<2)|j] last read by this same thread in stage_21 — safe
#pragma unroll
        for (int j = 0; j < 4; ++j) sm.slab[(t << 2) | j] = r[j];
    }
}

extern "C" __global__ void __launch_bounds__(NTHR)
qr_all(const float* __restrict__ x, const float* __restrict__ J,
       const float* __restrict__ g, float* __restrict__ out,
       float2* __restrict__ psi, float* __restrict__ P,
       int* __restrict__ wf) {
    __shared__ Smem sm;
    const int w = blockIdx.x;
    const int t = threadIdx.x;
    const int wid = (w << 2) | (t >> 6);
    const float dt = 0.1f;   // EVO_TIME / N_TROTTER

    if (t < 64) {
        float phi = 0.0f;
        for (int i = 0; i < 6; ++i) {
            const float h = 0.5f * J[i] * dt;
            phi += ((t >> i) & 1) ? h : -h;
        }
        float sn, cs; __sincosf(phi, &sn, &cs);
        sm.tabLo[t] = make_float2(cs, sn);
    } else if (t < 192) {
        const int v = t - 64;
        float phi = 0.0f;
        for (int i = 0; i < 7; ++i) {
            const float h = 0.5f * J[6 + i] * dt;
            phi += ((v >> i) & 1) ? h : -h;
        }
        float sn, cs; __sincosf(phi, &sn, &cs);
        sm.tabHi[v] = make_float2(cs, sn);
    }
    if (t < 48) sm.red[t] = 0.0f;
    float cc[NQ], ss[NQ];
#pragma unroll
    for (int i = 0; i < NQ; ++i) __sincosf(0.5f * g[i] * dt, &ss[i], &cc[i]);
    __syncthreads();

    int bar = 0;
    // Phase 1 (A): init + ZZ_1 + RX_1{0..9}
    phaseA<true>(sm, psi, w, t, cc, ss);
    arrive(wf, wid, ++bar);
    // Overlap phase-1 wait: precompute epilogue sincos (7 tasks/thread).
    float esn[7], ecs[7];
#pragma unroll
    for (int k = 0; k < 7; ++k) {
        const int task = w * NTHR + t + (k << 12);
        const int b = task / NQ;
        const int i = task - b * NQ;
        __sincosf(x[b * NQ + 13 - i], &esn[k], &ecs[k]);
    }
    waitrel(wf, bar);

    // Phases 2..10: B' on odd sstep, A on even
    for (int sstep = 1; sstep <= 9; ++sstep) {
        if (sstep & 1) {
            if (sstep == 9) {
                phaseB<true>(sm, psi, w, t, cc, ss);
                arrive(wf, wid, ++bar);
                // Overlap: reductions for q NOT in {4..7} (leftover commutes).
                // Slab bits: q0..3 -> 0..3, q8..13 -> 4..9.
                __syncthreads();
#pragma unroll
                for (int q = 0; q <= 3; ++q) reduce_qubit(sm, q, 13 - q, t);
#pragma unroll
                for (int q = 8; q <= 13; ++q) reduce_qubit(sm, q - 4, 13 - q, t);
                waitrel(wf, bar);
            } else {
                phaseB<false>(sm, psi, w, t, cc, ss);
                arrive(wf, wid, ++bar);
                waitrel(wf, bar);
            }
        } else {
            phaseA<false>(sm, psi, w, t, cc, ss);
            arrive(wf, wid, ++bar);
            waitrel(wf, bar);
        }
    }

    // Phase 11 (A): leftover RX_10{4..7} + reductions q4..7 + partial store
    {
        float2 r[4];
        ld4c(&psi[(w << 10) | (t << 2)], r);
#pragma unroll
        for (int b = 2; b < 6; ++b) {
#pragma unroll
            for (int j = 0; j < 4; ++j) bfly_shfl(r[j], 1 << b, cc[2 + b], ss[2 + b]);
        }
        __syncthreads();
#pragma unroll
        for (int j = 0; j < 4; ++j) sm.slab[(t << 2) | j] = r[j];
        __syncthreads();
#pragma unroll
        for (int q = 4; q <= 7; ++q) reduce_qubit(sm, q, 13 - q, t);
        __syncthreads();
        if (t < 42) stf(&P[t * NWG + w], sm.red[t]);   // transposed partials
        arrive(wf, wid, ++bar);
        waitrel(wf, bar);
    }

    // Epilogue: batched gather of 768 partial slots (rows 42..47 unused) ->
    // LDS -> 42 sums (unused rows summed but never read).
    float* sumbuf = (float*)sm.slab;
    {
        float r0, r1, r2;
        ldf3(&P[t], r0, r1, r2);
        sumbuf[t] = r0; sumbuf[t + 256] = r1; sumbuf[t + 512] = r2;
    }
    __syncthreads();
    float cv = 0.0f;
    if (t < 42) {
#pragma unroll
        for (int k = 0; k < NWG; ++k) cv += sumbuf[t * NWG + k];
    }
    __syncthreads();
    if (t < 42) sm.red[t] = cv;
    __syncthreads();

    // Batched outputs (sincos precomputed during phase-1 wait)
#pragma unroll
    for (int k = 0; k < 7; ++k) {
        const int task = w * NTHR + t + (k << 12);
        const int b = task / NQ;
        const int i = task - b * NQ;
        const float cr = sm.red[3 * i + 0];
        const float ci = sm.red[3 * i + 1];
        const float zz = sm.red[3 * i + 2];
        const float sn = esn[k], cs = ecs[k];
        float* o = out + b * (3 * NQ) + 3 * i;
        o[0] = 2.0f * (cs * cr - sn * ci);
        o[1] = 2.0f * (sn * cr + cs * ci);
        o[2] = zz;
    }
}

extern "C" void kernel_launch(void* const* d_in, const int* in_sizes, int n_in,
                              void* d_out, int out_size, void* d_ws, size_t ws_size,
                              hipStream_t stream) {
    const float* x = (const float*)d_in[0];
    const float* J = (const float*)d_in[1];
    const float* g = (const float*)d_in[2];
    float* out = (float*)d_out;
    char* ws   = (char*)d_ws;
    float2* psi = (float2*)ws;                                    // 128 KiB
    int*    wf  = (int*)(ws + DIMQ * sizeof(float2));             // 64 flags @256B
    float*  P   = (float*)(ws + DIMQ * sizeof(float2) + NWAVE * FSTR * 4); // 768 fl
    (void)in_sizes; (void)n_in; (void)out_size; (void)ws_size;

    // Single dispatch; no memset needed (phase-numbered flags, poison-safe).
    hipLaunchKernelGGL(qr_all, dim3(NWG), dim3(NTHR), 0, stream,
                       x, J, g, out, psi, P, wf);
}

// Round 11
// 93.807 us; speedup vs baseline: 1.3362x; 1.1041x over previous
//
#include <hip/hip_runtime.h>

#define NQ     14
#define DIMQ   16384
#define NWG    16
#define NTHR   256

typedef float vfloat4 __attribute__((ext_vector_type(4)));

struct Smem {
    float2 slab[1024];   // 8 KiB staging slab (reused as float sumbuf)
    float2 tabLo[64];    // e^{i phi} for ZZ couplers 0..5
    float2 tabHi[128];   // e^{i phi} for ZZ couplers 6..12
    float  red[48];      // this WG's partial sums of the 42 constants
};

// ---------------------------------------------------------------------------
// Self-validating dataflow sync: phase p stores amp + B_p (B alternates ±4,
// |amp| <= 1). Reader validates v*B_p > 8 (fresh bias) and retries; the 0xAA
// workspace poison (~ -3e-13) fails both biases. Reader-of-k and writer-of-k
// in a phase are the same WG, so k's next-phase writer validates k's current
// bias only after this WG already read k -> no WAR hazard, no bias aliasing.
// ---------------------------------------------------------------------------

// validated coherent load of 8 contiguous floats (4 float2), then decode
__device__ __forceinline__ void ld8v(const float2* p, float rb, float2 r[4]) {
    vfloat4 a, b;
    for (;;) {
        asm volatile("global_load_dwordx4 %0, %2, off sc0 sc1\n\t"
                     "global_load_dwordx4 %1, %2, off offset:16 sc0 sc1\n\t"
                     "s_waitcnt vmcnt(0)"
                     : "=&v"(a), "=&v"(b) : "v"(p) : "memory");
        float m0 = fminf(fminf(a.x * rb, a.y * rb), fminf(a.z * rb, a.w * rb));
        float m1 = fminf(fminf(b.x * rb, b.y * rb), fminf(b.z * rb, b.w * rb));
        bool ok = fminf(m0, m1) > 8.0f;
        if (__ballot(!ok) == 0ull) break;
        __builtin_amdgcn_s_sleep(1);
    }
    r[0] = make_float2(a.x - rb, a.y - rb); r[1] = make_float2(a.z - rb, a.w - rb);
    r[2] = make_float2(b.x - rb, b.y - rb); r[3] = make_float2(b.z - rb, b.w - rb);
}
// encoded coherent stores
__device__ __forceinline__ float2 d2f2(double d) { union { double d; float2 f; } u; u.d = d; return u.f; }
__device__ __forceinline__ double f22d(float2 f) { union { double d; float2 f; } u; u.f = f; return u.d; }
__device__ __forceinline__ void st2b(float2* p, float2 v, float wb) {
    float2 e = make_float2(v.x + wb, v.y + wb);
    asm volatile("global_store_dwordx2 %0, %1, off sc0 sc1"
                 : : "v"(p), "v"(f22d(e)) : "memory");
}
__device__ __forceinline__ void st8b(float2* p, const float2 r[4], float wb) {
    vfloat4 a, b;
    a.x = r[0].x + wb; a.y = r[0].y + wb; a.z = r[1].x + wb; a.w = r[1].y + wb;
    b.x = r[2].x + wb; b.y = r[2].y + wb; b.z = r[3].x + wb; b.w = r[3].y + wb;
    asm volatile("global_store_dwordx4 %0, %1, off sc0 sc1\n\t"
                 "global_store_dwordx4 %0, %2, off offset:16 sc0 sc1"
                 : : "v"(p), "v"(a), "v"(b) : "memory");
}
__device__ __forceinline__ void stfb(float* p, float v, float wb) {
    float e = v + wb;
    asm volatile("global_store_dword %0, %1, off sc0 sc1" : : "v"(p), "v"(e) : "memory");
}
// validated 3-strided-float gather for the epilogue partials (third masked:
// pad rows 672..767 are never written — validating them would livelock)
__device__ __forceinline__ void ld3v(const float* p, float rb, bool use2,
                                     float& r0, float& r1, float& r2) {
    for (;;) {
        asm volatile("global_load_dword %0, %3, off sc0 sc1\n\t"
                     "global_load_dword %1, %3, off offset:1024 sc0 sc1\n\t"
                     "global_load_dword %2, %3, off offset:2048 sc0 sc1\n\t"
                     "s_waitcnt vmcnt(0)"
                     : "=&v"(r0), "=&v"(r1), "=&v"(r2) : "v"(p) : "memory");
        float m = fminf(r0 * rb, r1 * rb);
        if (use2) m = fminf(m, r2 * rb);
        bool ok = m > 8.0f;
        if (__ballot(!ok) == 0ull) break;
        __builtin_amdgcn_s_sleep(1);
    }
    r0 -= rb; r1 -= rb; r2 -= rb;
}

// ---------------- gate math ------------------------------------------------
__device__ __forceinline__ float2 cmulf(float2 a, float2 b) {
    return make_float2(a.x * b.x - a.y * b.y, a.x * b.y + a.y * b.x);
}
__device__ __forceinline__ void bfly(float2& p0, float2& p1, float c, float s) {
    float2 n0 = make_float2(c * p0.x + s * p1.y, c * p0.y - s * p1.x);
    float2 n1 = make_float2(c * p1.x + s * p0.y, c * p1.y - s * p0.x);
    p0 = n0; p1 = n1;
}
__device__ __forceinline__ void bfly_shfl(float2& p, int mask, float c, float s) {
    float qx = __shfl_xor(p.x, mask);
    float qy = __shfl_xor(p.y, mask);
    p = make_float2(c * p.x + s * qy, c * p.y - s * qx);
}
__device__ __forceinline__ void zz_apply(const Smem& sm, float2& a, int k) {
    int d = (k ^ (k >> 1)) & 0x1FFF;
    float2 rot = cmulf(sm.tabLo[d & 63], sm.tabHi[d >> 6]);
    a = cmulf(a, rot);
}
// mapping1: m=(t<<2)|j (regs = m bits 0,1)  <->  mapping2: m=t|(j<<8)
__device__ __forceinline__ void stage_12(float2* slab, float2 r[4], int t) {
    __syncthreads();
#pragma unroll
    for (int j = 0; j < 4; ++j) slab[(t << 2) | j] = r[j];
    __syncthreads();
#pragma unroll
    for (int j = 0; j < 4; ++j) r[j] = slab[t | (j << 8)];
}
__device__ __forceinline__ void stage_21(float2* slab, float2 r[4], int t) {
    __syncthreads();
#pragma unroll
    for (int j = 0; j < 4; ++j) slab[t | (j << 8)] = r[j];
    __syncthreads();
#pragma unroll
    for (int j = 0; j < 4; ++j) r[j] = slab[(t << 2) | j];
}
// Reduce triple i over the WG's slab; qubit at slab bit sb.
__device__ __forceinline__ void reduce_qubit(Smem& sm, int sb, int i, int t) {
    float cr = 0.f, ci = 0.f, z = 0.f;
#pragma unroll
    for (int j = 0; j < 4; ++j) {
        const int m = (t << 2) | j;
        const float2 a = sm.slab[m];
        const float n = a.x * a.x + a.y * a.y;
        if ((m >> sb) & 1) {
            z -= n;
        } else {
            z += n;
            const float2 b = sm.slab[m ^ (1 << sb)];
            cr += a.x * b.x + a.y * b.y;
            ci += a.x * b.y - a.y * b.x;
        }
    }
#pragma unroll
    for (int off = 32; off; off >>= 1) {
        cr += __shfl_down(cr, off);
        ci += __shfl_down(ci, off);
        z  += __shfl_down(z, off);
    }
    if ((t & 63) == 0) {
        atomicAdd(&sm.red[3 * i + 0], cr);
        atomicAdd(&sm.red[3 * i + 1], ci);
        atomicAdd(&sm.red[3 * i + 2], z);
    }
}

// ---- Layout A: k = (w<<10)|m. WG w = qubits 10..13; local 0..9.
template <bool FIRST>
__device__ void phaseA(Smem& sm, float2* psi, int w, int t,
                       const float* c, const float* s, float rb, float wb) {
    float2 r[4];
    if (FIRST) {
#pragma unroll
        for (int j = 0; j < 4; ++j) r[j] = make_float2(0.0078125f, 0.0f);
    } else {
        ld8v(&psi[(w << 10) | (t << 2)], rb, r);
#pragma unroll
        for (int b = 2; b < 6; ++b) {   // leftover RX_s{4..7}
#pragma unroll
            for (int j = 0; j < 4; ++j) bfly_shfl(r[j], 1 << b, c[2 + b], s[2 + b]);
        }
    }
#pragma unroll
    for (int j = 0; j < 4; ++j) zz_apply(sm, r[j], (w << 10) | (t << 2) | j);
    bfly(r[0], r[1], c[0], s[0]); bfly(r[2], r[3], c[0], s[0]);
    bfly(r[0], r[2], c[1], s[1]); bfly(r[1], r[3], c[1], s[1]);
#pragma unroll
    for (int b = 0; b < 6; ++b) {
#pragma unroll
        for (int j = 0; j < 4; ++j) bfly_shfl(r[j], 1 << b, c[2 + b], s[2 + b]);
    }
    stage_12(sm.slab, r, t);   // mapping2: regs = q8,q9
    bfly(r[0], r[1], c[8], s[8]); bfly(r[2], r[3], c[8], s[8]);
    bfly(r[0], r[2], c[9], s[9]); bfly(r[1], r[3], c[9], s[9]);
#pragma unroll
    for (int j = 0; j < 4; ++j) st2b(&psi[(w << 10) | t | (j << 8)], r[j], wb);
}

// ---- Layout B': k = (hi6<<8)|(w<<4)|lo4. WG w = qubits 4..7;
// local {0..3,8..13}; 32 B contiguous per thread.
// RX_s{10..13}, ZZ_{s+1}, RX_{s+1}{0..3,8..13}. Leftover: RX_{s+1}{4..7}.
template <bool KEEPSLAB>
__device__ void phaseB(Smem& sm, float2* psi, int w, int t,
                       const float* c, const float* s, float rb, float wb) {
    float2 r[4];
    const int kbase = ((t >> 2) << 8) | (w << 4) | ((t & 3) << 2);
    ld8v(&psi[kbase], rb, r);
#pragma unroll
    for (int j = 0; j < 4; ++j) bfly_shfl(r[j], 16, c[10], s[10]);
#pragma unroll
    for (int j = 0; j < 4; ++j) bfly_shfl(r[j], 32, c[11], s[11]);
    stage_12(sm.slab, r, t);   // mapping2: regs = q12,q13
    bfly(r[0], r[1], c[12], s[12]); bfly(r[2], r[3], c[12], s[12]);
    bfly(r[0], r[2], c[13], s[13]); bfly(r[1], r[3], c[13], s[13]);
#pragma unroll
    for (int j = 0; j < 4; ++j) {
        const int m = t | (j << 8);
        zz_apply(sm, r[j], ((m >> 4) << 8) | (w << 4) | (m & 15));
    }
    bfly(r[0], r[1], c[12], s[12]); bfly(r[2], r[3], c[12], s[12]);
    bfly(r[0], r[2], c[13], s[13]); bfly(r[1], r[3], c[13], s[13]);
#pragma unroll
    for (int b = 0; b < 4; ++b) {
#pragma unroll
        for (int j = 0; j < 4; ++j) bfly_shfl(r[j], 1 << b, c[b], s[b]);
    }
#pragma unroll
    for (int j = 0; j < 4; ++j) bfly_shfl(r[j], 16, c[8], s[8]);
#pragma unroll
    for (int j = 0; j < 4; ++j) bfly_shfl(r[j], 32, c[9], s[9]);
    stage_21(sm.slab, r, t);   // back to mapping1
#pragma unroll
    for (int j = 0; j < 4; ++j) bfly_shfl(r[j], 16, c[10], s[10]);
#pragma unroll
    for (int j = 0; j < 4; ++j) bfly_shfl(r[j], 32, c[11], s[11]);
    st8b(&psi[kbase], r, wb);
    if (KEEPSLAB) {
        // slab[(t<<2)|j] last read by this same thread in stage_21 — safe;
        // stores TRUE amps (encode only happens inside store helpers)
#pragma unroll
        for (int j = 0; j < 4; ++j) sm.slab[(t << 2) | j] = r[j];
    }
}

extern "C" __global__ void __launch_bounds__(NTHR)
qr_all(const float* __restrict__ x, const float* __restrict__ J,
       const float* __restrict__ g, float* __restrict__ out,
       float2* __restrict__ psi, float* __restrict__ P) {
    __shared__ Smem sm;
    const int w = blockIdx.x;
    const int t = threadIdx.x;
    const float dt = 0.1f;   // EVO_TIME / N_TROTTER

    if (t < 64) {
        float phi = 0.0f;
        for (int i = 0; i < 6; ++i) {
            const float h = 0.5f * J[i] * dt;
            phi += ((t >> i) & 1) ? h : -h;
        }
        float sn, cs; __sincosf(phi, &sn, &cs);
        sm.tabLo[t] = make_float2(cs, sn);
    } else if (t < 192) {
        const int v = t - 64;
        float phi = 0.0f;
        for (int i = 0; i < 7; ++i) {
            const float h = 0.5f * J[6 + i] * dt;
            phi += ((v >> i) & 1) ? h : -h;
        }
        float sn, cs; __sincosf(phi, &sn, &cs);
        sm.tabHi[v] = make_float2(cs, sn);
    }
    if (t < 48) sm.red[t] = 0.0f;
    float cc[NQ], ss[NQ];
#pragma unroll
    for (int i = 0; i < NQ; ++i) __sincosf(0.5f * g[i] * dt, &ss[i], &cc[i]);
    __syncthreads();

    // Bias schedule: phase p writes bias (p odd ? -4 : +4); reader uses the
    // previous phase's write bias. Phases: 1 = A<FIRST>, 2..10 alternate
    // B'/A (sstep 1..9, p = sstep+1), 11 = final A-type.
    // Phase 1 (p=1, wb=-4): init + ZZ_1 + RX_1{0..9}
    phaseA<true>(sm, psi, w, t, cc, ss, 0.0f, -4.0f);

    // Precompute epilogue sincos here: gives phase-1 writers time to land
    // before phase-2 loads start validating. 7 tasks/thread.
    float esn[7], ecs[7];
#pragma unroll
    for (int k = 0; k < 7; ++k) {
        const int task = w * NTHR + t + (k << 12);
        const int b = task / NQ;
        const int i = task - b * NQ;
        __sincosf(x[b * NQ + 13 - i], &esn[k], &ecs[k]);
    }

    // Phases 2..10: B' on odd sstep, A on even. p = sstep+1.
    for (int sstep = 1; sstep <= 9; ++sstep) {
        const float wb = ((sstep + 1) & 1) ? -4.0f : 4.0f;
        const float rb = -wb;
        if (sstep & 1) {
            if (sstep == 9) {
                phaseB<true>(sm, psi, w, t, cc, ss, rb, wb);
                // Reductions for q NOT in {4..7} (leftover RX{4..7} commutes).
                // Slab bits: q0..3 -> 0..3, q8..13 -> 4..9.
                __syncthreads();
#pragma unroll
                for (int q = 0; q <= 3; ++q) reduce_qubit(sm, q, 13 - q, t);
#pragma unroll
                for (int q = 8; q <= 13; ++q) reduce_qubit(sm, q - 4, 13 - q, t);
            } else {
                phaseB<false>(sm, psi, w, t, cc, ss, rb, wb);
            }
        } else {
            phaseA<false>(sm, psi, w, t, cc, ss, rb, wb);
        }
    }

    // Phase 11 (p=11, rb=+4 from p=10): leftover RX_10{4..7} + reductions
    // q4..7 + biased partial store (wb=-4). No psi write-back.
    {
        float2 r[4];
        ld8v(&psi[(w << 10) | (t << 2)], 4.0f, r);
#pragma unroll
        for (int b = 2; b < 6; ++b) {
#pragma unroll
            for (int j = 0; j < 4; ++j) bfly_shfl(r[j], 1 << b, cc[2 + b], ss[2 + b]);
        }
        __syncthreads();
#pragma unroll
        for (int j = 0; j < 4; ++j) sm.slab[(t << 2) | j] = r[j];
        __syncthreads();
#pragma unroll
        for (int q = 4; q <= 7; ++q) reduce_qubit(sm, q, 13 - q, t);
        __syncthreads();
        if (t < 42) stfb(&P[t * NWG + w], sm.red[t], -4.0f);  // transposed
    }

    // Epilogue: validated gather of 768 partial slots (P rows 42..47 never
    // written -> masked out of validation) -> LDS -> 42 sums.
    float* sumbuf = (float*)sm.slab;
    {
        float r0, r1, r2;
        ld3v(&P[t], -4.0f, t < 160, r0, r1, r2);
        sumbuf[t] = r0; sumbuf[t + 256] = r1; sumbuf[t + 512] = r2;
    }
    __syncthreads();
    float cv = 0.0f;
    if (t < 42) {
#pragma unroll
        for (int k = 0; k < NWG; ++k) cv += sumbuf[t * NWG + k];
    }
    __syncthreads();
    if (t < 42) sm.red[t] = cv;
    __syncthreads();

    // Batched outputs (sincos precomputed after phase 1)
#pragma unroll
    for (int k = 0; k < 7; ++k) {
        const int task = w * NTHR + t + (k << 12);
        const int b = task / NQ;
        const int i = task - b * NQ;
        const float cr = sm.red[3 * i + 0];
        const float ci = sm.red[3 * i + 1];
        const float zz = sm.red[3 * i + 2];
        const float sn = esn[k], cs = ecs[k];
        float* o = out + b * (3 * NQ) + 3 * i;
        o[0] = 2.0f * (cs * cr - sn * ci);
        o[1] = 2.0f * (sn * cr + cs * ci);
        o[2] = zz;
    }
}

extern "C" void kernel_launch(void* const* d_in, const int* in_sizes, int n_in,
                              void* d_out, int out_size, void* d_ws, size_t ws_size,
                              hipStream_t stream) {
    const float* x = (const float*)d_in[0];
    const float* J = (const float*)d_in[1];
    const float* g = (const float*)d_in[2];
    float* out = (float*)d_out;
    char* ws   = (char*)d_ws;
    float2* psi = (float2*)ws;                                  // 128 KiB
    float*  P   = (float*)(ws + DIMQ * sizeof(float2));         // 768 floats
    (void)in_sizes; (void)n_in; (void)out_size; (void)ws_size;

    // Single dispatch; no memset needed — the 0xAA poison fails both bias
    // validations, so all psi/P reads self-synchronize.
    hipLaunchKernelGGL(qr_all, dim3(NWG), dim3(NTHR), 0, stream,
                       x, J, g, out, psi, P);
}